// Round 16
// baseline (815.234 us; speedup 1.0000x reference)
//
#include <hip/hip_runtime.h>
#include <hip/hip_fp16.h>

#define WPB 8     // waves per sage block (512 threads)
#define PADK 136  // f16 elems per LDS row: 128 + 8 pad (16B-aligned rows)
#define BSH 8     // bucket shift: 256 nodes per bucket
#define BNODES 256
#define SC_BLOCKS 256
#define HIST_BLOCKS 256

typedef _Float16 half8 __attribute__((ext_vector_type(8)));
typedef float floatx4 __attribute__((ext_vector_type(4)));

#define TS16(v) (((((v)[0] + (v)[1]) + ((v)[2] + (v)[3])) + (((v)[4] + (v)[5]) + ((v)[6] + (v)[7]))) + \
                 ((((v)[8] + (v)[9]) + ((v)[10] + (v)[11])) + (((v)[12] + (v)[13]) + ((v)[14] + (v)[15]))))

// ---------------- pre: hist (blocks 0..255) + x->f16 cvt (rest) + last-block bucket scan ----------------
__global__ __launch_bounds__(256) void gnn_pre(const int* __restrict__ dst,
                                               int* __restrict__ bkt_cnt, int nbkt, int E,
                                               const int* __restrict__ batch,
                                               float* __restrict__ gcnt, int N,
                                               const float4* __restrict__ xin,
                                               ushort4* __restrict__ x16o, int n4,
                                               __half* __restrict__ x16,
                                               __half* __restrict__ hA,
                                               __half* __restrict__ hB,
                                               int* __restrict__ done,
                                               int* __restrict__ bkt_base,
                                               int* __restrict__ bkt_cur,
                                               int* __restrict__ row_ptr) {
    int tid = threadIdx.x;
    if (blockIdx.x < HIST_BLOCKS) {
        __shared__ int h[512];
        __shared__ int gb[64];
        for (int i = tid; i < nbkt; i += 256) h[i] = 0;
        if (tid < 64) gb[tid] = 0;
        __syncthreads();
        const int stride = HIST_BLOCKS * 256;
        for (int e = blockIdx.x * 256 + tid; e < E; e += stride)
            atomicAdd(&h[dst[e] >> BSH], 1);
        for (int i = blockIdx.x * 256 + tid; i < N; i += stride)
            atomicAdd(&gb[batch[i]], 1);
        __syncthreads();
        for (int i = tid; i < nbkt; i += 256) {
            int v = h[i];
            if (v) atomicAdd(&bkt_cnt[i], v);
        }
        if (tid < 64) {
            int v = gb[tid];
            if (v) atomicAdd(&gcnt[tid], (float)v);
        }
        if (blockIdx.x == 0 && tid < 64) {  // zero sentinel row N of x16, hA, hB
            x16[(size_t)N * 64 + tid] = __ushort_as_half((unsigned short)0);
            hA[(size_t)N * 64 + tid] = __ushort_as_half((unsigned short)0);
            hB[(size_t)N * 64 + tid] = __ushort_as_half((unsigned short)0);
        }
    } else {
        int i = (blockIdx.x - HIST_BLOCKS) * 256 + tid;
        if (i < n4) {
            float4 f = xin[i];
            ushort4 o;
            o.x = __half_as_ushort(__float2half(f.x));
            o.y = __half_as_ushort(__float2half(f.y));
            o.z = __half_as_ushort(__float2half(f.z));
            o.w = __half_as_ushort(__float2half(f.w));
            x16o[i] = o;
        }
    }
    // ---- last-block-done: final block performs the bucket exclusive scan inline ----
    __shared__ int sticket;
    __threadfence();
    __syncthreads();
    if (tid == 0) sticket = atomicAdd(done, 1);
    __syncthreads();
    if (sticket == (int)gridDim.x - 1 && tid < 64) {
        int lane = tid;
        int carry = 0;
        for (int base = 0; base < nbkt; base += 64) {
            int idx = base + lane;
            int v = (idx < nbkt) ? bkt_cnt[idx] : 0;
            int x = v;
#pragma unroll
            for (int off = 1; off < 64; off <<= 1) {
                int y = __shfl_up(x, off);
                if (lane >= off) x += y;
            }
            if (idx < nbkt) {
                bkt_base[idx] = carry + (x - v);
                bkt_cur[idx] = carry + (x - v);
            }
            carry += __shfl(x, 63);
        }
        if (lane == 0) {
            bkt_base[nbkt] = carry;
            row_ptr[N] = carry;
        }
    }
}

// ---------------- block-aggregated two-phase scatter (packed uint32) ----------------
__global__ __launch_bounds__(256) void gnn_bkt_scatter(const int* __restrict__ src,
                                                       const int* __restrict__ dst,
                                                       int* __restrict__ bkt_cur,
                                                       unsigned int* __restrict__ pairs,
                                                       int E, int nbkt) {
    __shared__ int hist[512];
    __shared__ int cur[512];
    int tid = threadIdx.x;
    int chunk = (E + gridDim.x - 1) / gridDim.x;
    int e0 = blockIdx.x * chunk;
    int e1 = min(E, e0 + chunk);
    for (int i = tid; i < nbkt; i += 256) hist[i] = 0;
    __syncthreads();
    for (int e = e0 + tid; e < e1; e += 256) atomicAdd(&hist[dst[e] >> BSH], 1);
    __syncthreads();
    for (int b = tid; b < nbkt; b += 256) {
        int c = hist[b];
        cur[b] = c ? atomicAdd(&bkt_cur[b], c) : 0;
    }
    __syncthreads();
    for (int e = e0 + tid; e < e1; e += 256) {
        int d = dst[e];
        int b = d >> BSH;
        int p = atomicAdd(&cur[b], 1);
        pairs[p] = (unsigned int)src[e] | ((unsigned int)(d & (BNODES - 1)) << 24);
    }
}

// ---------------- per-bucket CSR finalize ----------------
__global__ __launch_bounds__(256) void gnn_bkt_csr(const unsigned int* __restrict__ pairs,
                                                   const int* __restrict__ bkt_base,
                                                   int* __restrict__ row_ptr,
                                                   float* __restrict__ inv_deg,
                                                   int* __restrict__ csr_src, int N) {
    __shared__ int hist[BNODES];
    __shared__ int excl[BNODES];
    __shared__ int cur[BNODES];
    int b = blockIdx.x;
    int base = bkt_base[b];
    int cnt = bkt_base[b + 1] - base;
    int nd0 = b << BSH;
    int tid = threadIdx.x;
    hist[tid] = 0;
    __syncthreads();
    for (int i = tid; i < cnt; i += 256) atomicAdd(&hist[pairs[base + i] >> 24], 1);
    __syncthreads();
    if (tid < 64) {
        int carry = 0;
#pragma unroll
        for (int c = 0; c < BNODES; c += 64) {
            int v = hist[c + tid];
            int x = v;
#pragma unroll
            for (int off = 1; off < 64; off <<= 1) {
                int y = __shfl_up(x, off);
                if (tid >= off) x += y;
            }
            excl[c + tid] = carry + (x - v);
            carry += __shfl(x, 63);
        }
    }
    __syncthreads();
    {
        int node = nd0 + tid;
        if (node < N) {
            row_ptr[node] = base + excl[tid];
            int d = hist[tid];
            inv_deg[node] = 1.0f / (float)(d > 1 ? d : 1);
        }
        cur[tid] = excl[tid];
    }
    __syncthreads();
    for (int i = tid; i < cnt; i += 256) {
        unsigned int u = pairs[base + i];
        int j = u >> 24;
        int pos = atomicAdd(&cur[j], 1);
        csr_src[base + pos] = (int)(u & 0xFFFFFFu);
    }
}

// ---------------- SAGE layer (R10/R14-verbatim body — do NOT reshape gather) ----------------
__global__ __launch_bounds__(512, 6) void gnn_sage(const __half* __restrict__ hin,
                                                   __half* __restrict__ hout,
                                                   const int* __restrict__ row_ptr,
                                                   const int* __restrict__ csr_src,
                                                   const float* __restrict__ inv_deg,
                                                   const float* __restrict__ Wl,
                                                   const float* __restrict__ bl,
                                                   const float* __restrict__ Wr, int n) {
    __shared__ _Float16 w_lds[64 * PADK];
    __shared__ _Float16 in_lds[WPB][16 * PADK];
    int tid = threadIdx.x, lane = tid & 63, wv = tid >> 6;
    for (int i = tid; i < 64 * 64; i += 512) {
        int k = i >> 6, nn = i & 63;
        w_lds[nn * PADK + k] = (_Float16)Wl[i];
        w_lds[nn * PADK + 64 + k] = (_Float16)Wr[i];
    }
    __syncthreads();
    int ngroups = (n + 15) >> 4;
    int g = blockIdx.x * WPB + wv;
    if (g >= ngroups) return;
    int m16 = lane & 15, quad = lane >> 4;
    float bias[4];
#pragma unroll
    for (int nt = 0; nt < 4; nt++) bias[nt] = bl[nt * 16 + m16];
    _Float16* my_in = in_lds[wv];
    const _Float16* hin16 = (const _Float16*)hin;
    int nd0 = g << 4;
    for (int j2 = 0; j2 < 16; j2 += 2) {
        int ndA = min(nd0 + j2, n - 1);
        int ndB = min(nd0 + j2 + 1, n - 1);
        int s0A = row_ptr[ndA], s1A = row_ptr[ndA + 1];
        int s0B = row_ptr[ndB], s1B = row_ptr[ndB + 1];
        float idgA = inv_deg[ndA], idgB = inv_deg[ndB];
        my_in[j2 * PADK + 64 + lane] = hin16[(size_t)ndA * 64 + lane];
        my_in[(j2 + 1) * PADK + 64 + lane] = hin16[(size_t)ndB * 64 + lane];
        float accA = 0.0f, accB = 0.0f;
        int cbA = min(64, s1A - s0A);
        int cbB = min(64, s1B - s0B);
        int eA = (lane < cbA) ? csr_src[s0A + lane] : n;
        int eB = (lane < cbB) ? csr_src[s0B + lane] : n;
#pragma unroll
        for (int ib = 0; ib < 4; ib++) {
            const int i0 = ib * 16;
            if (i0 < cbA) {
                float vA[16];
#pragma unroll
                for (int j = 0; j < 16; j++) {
                    int sj = __shfl(eA, i0 + j);
                    vA[j] = __half2float(hin[(size_t)sj * 64 + lane]);
                }
                accA += TS16(vA);
            }
            if (i0 < cbB) {
                float vB[16];
#pragma unroll
                for (int j = 0; j < 16; j++) {
                    int sj = __shfl(eB, i0 + j);
                    vB[j] = __half2float(hin[(size_t)sj * 64 + lane]);
                }
                accB += TS16(vB);
            }
        }
        for (int base = s0A + 64; base < s1A; base += 64) {
            int cb = min(64, s1A - base);
            int ei = (lane < cb) ? csr_src[base + lane] : n;
#pragma unroll
            for (int ib = 0; ib < 4; ib++) {
                const int i0 = ib * 16;
                if (i0 < cb) {
                    float v[16];
#pragma unroll
                    for (int j = 0; j < 16; j++) {
                        int s = __shfl(ei, i0 + j);
                        v[j] = __half2float(hin[(size_t)s * 64 + lane]);
                    }
                    accA += TS16(v);
                }
            }
        }
        for (int base = s0B + 64; base < s1B; base += 64) {
            int cb = min(64, s1B - base);
            int ei = (lane < cb) ? csr_src[base + lane] : n;
#pragma unroll
            for (int ib = 0; ib < 4; ib++) {
                const int i0 = ib * 16;
                if (i0 < cb) {
                    float v[16];
#pragma unroll
                    for (int j = 0; j < 16; j++) {
                        int s = __shfl(ei, i0 + j);
                        v[j] = __half2float(hin[(size_t)s * 64 + lane]);
                    }
                    accB += TS16(v);
                }
            }
        }
        my_in[j2 * PADK + lane] = (_Float16)(accA * idgA);
        my_in[(j2 + 1) * PADK + lane] = (_Float16)(accB * idgB);
    }
    half8 afrag[4];
    const _Float16* abase = my_in + m16 * PADK + quad * 8;
#pragma unroll
    for (int ks = 0; ks < 4; ks++) afrag[ks] = *(const half8*)(abase + ks * 32);
    floatx4 accv[4];
#pragma unroll
    for (int nt = 0; nt < 4; nt++) {
        accv[nt].x = 0.f; accv[nt].y = 0.f; accv[nt].z = 0.f; accv[nt].w = 0.f;
    }
#pragma unroll
    for (int nt = 0; nt < 4; nt++) {
        const _Float16* bbase = w_lds + (nt * 16 + m16) * PADK + quad * 8;
#pragma unroll
        for (int ks = 0; ks < 4; ks++) {
            half8 bfrag = *(const half8*)(bbase + ks * 32);
            accv[nt] = __builtin_amdgcn_mfma_f32_16x16x32_f16(afrag[ks], bfrag, accv[nt], 0, 0, 0);
        }
    }
#pragma unroll
    for (int nt = 0; nt < 4; nt++) {
#pragma unroll
        for (int r = 0; r < 4; r++) {
            int node = nd0 + quad * 4 + r;
            if (node < n) {
                float v = fmaxf(accv[nt][r] + bias[nt], 0.0f);
                hout[(size_t)node * 64 + nt * 16 + m16] = __float2half(v);
            }
        }
    }
}

// ---------------- SAGE layer 3 + fused global-mean-pool epilogue ----------------
__global__ __launch_bounds__(512, 6) void gnn_sage_pool(const __half* __restrict__ hin,
                                                        const int* __restrict__ row_ptr,
                                                        const int* __restrict__ csr_src,
                                                        const float* __restrict__ inv_deg,
                                                        const float* __restrict__ Wl,
                                                        const float* __restrict__ bl,
                                                        const float* __restrict__ Wr,
                                                        const int* __restrict__ batch,
                                                        float* __restrict__ gsum, int n) {
    __shared__ _Float16 w_lds[64 * PADK];
    __shared__ _Float16 in_lds[WPB][16 * PADK];
    int tid = threadIdx.x, lane = tid & 63, wv = tid >> 6;
    for (int i = tid; i < 64 * 64; i += 512) {
        int k = i >> 6, nn = i & 63;
        w_lds[nn * PADK + k] = (_Float16)Wl[i];
        w_lds[nn * PADK + 64 + k] = (_Float16)Wr[i];
    }
    __syncthreads();
    int ngroups = (n + 15) >> 4;
    int g = blockIdx.x * WPB + wv;
    if (g >= ngroups) return;
    int m16 = lane & 15, quad = lane >> 4;
    float bias[4];
#pragma unroll
    for (int nt = 0; nt < 4; nt++) bias[nt] = bl[nt * 16 + m16];
    _Float16* my_in = in_lds[wv];
    const _Float16* hin16 = (const _Float16*)hin;
    int nd0 = g << 4;
    for (int j2 = 0; j2 < 16; j2 += 2) {
        int ndA = min(nd0 + j2, n - 1);
        int ndB = min(nd0 + j2 + 1, n - 1);
        int s0A = row_ptr[ndA], s1A = row_ptr[ndA + 1];
        int s0B = row_ptr[ndB], s1B = row_ptr[ndB + 1];
        float idgA = inv_deg[ndA], idgB = inv_deg[ndB];
        my_in[j2 * PADK + 64 + lane] = hin16[(size_t)ndA * 64 + lane];
        my_in[(j2 + 1) * PADK + 64 + lane] = hin16[(size_t)ndB * 64 + lane];
        float accA = 0.0f, accB = 0.0f;
        int cbA = min(64, s1A - s0A);
        int cbB = min(64, s1B - s0B);
        int eA = (lane < cbA) ? csr_src[s0A + lane] : n;
        int eB = (lane < cbB) ? csr_src[s0B + lane] : n;
#pragma unroll
        for (int ib = 0; ib < 4; ib++) {
            const int i0 = ib * 16;
            if (i0 < cbA) {
                float vA[16];
#pragma unroll
                for (int j = 0; j < 16; j++) {
                    int sj = __shfl(eA, i0 + j);
                    vA[j] = __half2float(hin[(size_t)sj * 64 + lane]);
                }
                accA += TS16(vA);
            }
            if (i0 < cbB) {
                float vB[16];
#pragma unroll
                for (int j = 0; j < 16; j++) {
                    int sj = __shfl(eB, i0 + j);
                    vB[j] = __half2float(hin[(size_t)sj * 64 + lane]);
                }
                accB += TS16(vB);
            }
        }
        for (int base = s0A + 64; base < s1A; base += 64) {
            int cb = min(64, s1A - base);
            int ei = (lane < cb) ? csr_src[base + lane] : n;
#pragma unroll
            for (int ib = 0; ib < 4; ib++) {
                const int i0 = ib * 16;
                if (i0 < cb) {
                    float v[16];
#pragma unroll
                    for (int j = 0; j < 16; j++) {
                        int s = __shfl(ei, i0 + j);
                        v[j] = __half2float(hin[(size_t)s * 64 + lane]);
                    }
                    accA += TS16(v);
                }
            }
        }
        for (int base = s0B + 64; base < s1B; base += 64) {
            int cb = min(64, s1B - base);
            int ei = (lane < cb) ? csr_src[base + lane] : n;
#pragma unroll
            for (int ib = 0; ib < 4; ib++) {
                const int i0 = ib * 16;
                if (i0 < cb) {
                    float v[16];
#pragma unroll
                    for (int j = 0; j < 16; j++) {
                        int s = __shfl(ei, i0 + j);
                        v[j] = __half2float(hin[(size_t)s * 64 + lane]);
                    }
                    accB += TS16(v);
                }
            }
        }
        my_in[j2 * PADK + lane] = (_Float16)(accA * idgA);
        my_in[(j2 + 1) * PADK + lane] = (_Float16)(accB * idgB);
    }
    half8 afrag[4];
    const _Float16* abase = my_in + m16 * PADK + quad * 8;
#pragma unroll
    for (int ks = 0; ks < 4; ks++) afrag[ks] = *(const half8*)(abase + ks * 32);
    floatx4 accv[4];
#pragma unroll
    for (int nt = 0; nt < 4; nt++) {
        accv[nt].x = 0.f; accv[nt].y = 0.f; accv[nt].z = 0.f; accv[nt].w = 0.f;
    }
#pragma unroll
    for (int nt = 0; nt < 4; nt++) {
        const _Float16* bbase = w_lds + (nt * 16 + m16) * PADK + quad * 8;
#pragma unroll
        for (int ks = 0; ks < 4; ks++) {
            half8 bfrag = *(const half8*)(bbase + ks * 32);
            accv[nt] = __builtin_amdgcn_mfma_f32_16x16x32_f16(afrag[ks], bfrag, accv[nt], 0, 0, 0);
        }
    }
    // ---- fused pool epilogue ----
    int bFirst = batch[nd0];
    int bLast = batch[min(nd0 + 15, n - 1)];
    if (bFirst == bLast && nd0 + 15 < n) {
#pragma unroll
        for (int nt = 0; nt < 4; nt++) {
            float s = fmaxf(accv[nt][0] + bias[nt], 0.0f) + fmaxf(accv[nt][1] + bias[nt], 0.0f) +
                      fmaxf(accv[nt][2] + bias[nt], 0.0f) + fmaxf(accv[nt][3] + bias[nt], 0.0f);
            s += __shfl_xor(s, 16);
            s += __shfl_xor(s, 32);
            if (quad == 0) atomicAdd(&gsum[bFirst * 64 + nt * 16 + m16], s);
        }
    } else {
#pragma unroll
        for (int nt = 0; nt < 4; nt++) {
#pragma unroll
            for (int r = 0; r < 4; r++) {
                int node = nd0 + quad * 4 + r;
                if (node < n) {
                    int bg = batch[node];
                    float v = fmaxf(accv[nt][r] + bias[nt], 0.0f);
                    atomicAdd(&gsum[bg * 64 + nt * 16 + m16], v);
                }
            }
        }
    }
}

// ---------------- head ----------------
__global__ __launch_bounds__(256) void gnn_head(const float* __restrict__ gsum,
                                                const float* __restrict__ gcnt,
                                                const float* __restrict__ l0W,
                                                const float* __restrict__ l0b,
                                                const float* __restrict__ outW,
                                                const float* __restrict__ outb,
                                                float* __restrict__ out, int G, int OUT) {
    __shared__ float gm[64 * 64];
    __shared__ float t2[64 * 64];
    int tid = threadIdx.x;
    for (int i = tid; i < G * 64; i += 256) {
        int r = i >> 6;
        gm[i] = gsum[i] / fmaxf(gcnt[r], 1.0f);
    }
    __syncthreads();
    for (int i = tid; i < G * 64; i += 256) {
        int r = i >> 6, c = i & 63;
        float s = l0b[c];
#pragma unroll 8
        for (int k = 0; k < 64; k++) s += gm[(r << 6) + k] * l0W[(k << 6) + c];
        t2[i] = fmaxf(s, 0.0f);
    }
    __syncthreads();
    for (int i = tid; i < G * OUT; i += 256) {
        int r = i / OUT, c = i - r * OUT;
        float s = outb[c];
#pragma unroll 8
        for (int k = 0; k < 64; k++) s += t2[(r << 6) + k] * outW[k * OUT + c];
        out[i] = s;
    }
}

extern "C" void kernel_launch(void* const* d_in, const int* in_sizes, int n_in,
                              void* d_out, int out_size, void* d_ws, size_t ws_size,
                              hipStream_t stream) {
    const float* x = (const float*)d_in[0];
    const int* ei = (const int*)d_in[1];
    const int* batch = (const int*)d_in[2];
    const float* Wl[3] = {(const float*)d_in[3], (const float*)d_in[6], (const float*)d_in[9]};
    const float* bl[3] = {(const float*)d_in[4], (const float*)d_in[7], (const float*)d_in[10]};
    const float* Wr[3] = {(const float*)d_in[5], (const float*)d_in[8], (const float*)d_in[11]};
    const float* l0W = (const float*)d_in[12];
    const float* l0b = (const float*)d_in[13];
    const float* outW = (const float*)d_in[14];
    const float* outb = (const float*)d_in[15];

    int N = in_sizes[2];
    int E = in_sizes[1] / 2;
    int OUT = 10;
    int G = out_size / OUT;
    const int* src = ei;
    const int* dst = ei + E;
    int NBKT = (N + BNODES - 1) >> BSH;

    char* ws = (char*)d_ws;
    size_t off = 0;
    auto alloc = [&](size_t b) -> char* {
        char* p = ws + off;
        off = (off + b + 255) & ~(size_t)255;
        return p;
    };
    int* row_ptr = (int*)alloc((size_t)(N + 1) * 4);
    int* csr_src = (int*)alloc((size_t)E * 4);
    float* inv_deg = (float*)alloc((size_t)N * 4);
    // contiguous zero region: bkt_cnt | gcnt | gsum | done (one memset)
    size_t zoff = off;
    int* bkt_cnt = (int*)alloc((size_t)NBKT * 4);
    float* gcnt = (float*)alloc((size_t)G * 4);
    float* gsum = (float*)alloc((size_t)G * 64 * 4);
    int* done = (int*)alloc(256);
    size_t zlen = off - zoff;
    int* bkt_base = (int*)alloc((size_t)(NBKT + 1) * 4);
    int* bkt_cur = (int*)alloc((size_t)NBKT * 4);
    unsigned int* pairs = (unsigned int*)alloc((size_t)E * 4);
    __half* x16 = (__half*)alloc((size_t)(N + 1) * 64 * 2);  // +1 sentinel row
    __half* hA = (__half*)alloc((size_t)(N + 1) * 64 * 2);
    __half* hB = (__half*)alloc((size_t)(N + 1) * 64 * 2);

    hipMemsetAsync(ws + zoff, 0, zlen, stream);

    int n4 = N * 64 / 4;
    int pre_blocks = HIST_BLOCKS + (n4 + 255) / 256;
    gnn_pre<<<pre_blocks, 256, 0, stream>>>(dst, bkt_cnt, NBKT, E, batch, gcnt, N,
                                            (const float4*)x, (ushort4*)x16, n4,
                                            x16, hA, hB, done, bkt_base, bkt_cur, row_ptr);
    gnn_bkt_scatter<<<SC_BLOCKS, 256, 0, stream>>>(src, dst, bkt_cur, pairs, E, NBKT);
    gnn_bkt_csr<<<NBKT, 256, 0, stream>>>(pairs, bkt_base, row_ptr, inv_deg, csr_src, N);

    int ngroups = (N + 15) >> 4;
    int sage_blocks = (ngroups + WPB - 1) / WPB;
    gnn_sage<<<sage_blocks, 512, 0, stream>>>(x16, hA, row_ptr, csr_src, inv_deg,
                                              Wl[0], bl[0], Wr[0], N);
    gnn_sage<<<sage_blocks, 512, 0, stream>>>(hA, hB, row_ptr, csr_src, inv_deg,
                                              Wl[1], bl[1], Wr[1], N);
    gnn_sage_pool<<<sage_blocks, 512, 0, stream>>>(hB, row_ptr, csr_src, inv_deg,
                                                   Wl[2], bl[2], Wr[2], batch, gsum, N);

    gnn_head<<<1, 256, 0, stream>>>(gsum, gcnt, l0W, l0b, outW, outb, (float*)d_out, G, OUT);
}

// Round 17
// 350.765 us; speedup vs baseline: 2.3242x; 2.3242x over previous
//
#include <hip/hip_runtime.h>
#include <hip/hip_fp16.h>

#define WPB 8     // waves per sage block (512 threads)
#define PADK 136  // f16 elems per LDS row: 128 + 8 pad (16B-aligned rows)
#define BSH 8     // bucket shift: 256 nodes per bucket
#define BNODES 256
#define SC_BLOCKS 256
#define HIST_BLOCKS 256

typedef _Float16 half8 __attribute__((ext_vector_type(8)));
typedef float floatx4 __attribute__((ext_vector_type(4)));

#define TS16(v) (((((v)[0] + (v)[1]) + ((v)[2] + (v)[3])) + (((v)[4] + (v)[5]) + ((v)[6] + (v)[7]))) + \
                 ((((v)[8] + (v)[9]) + ((v)[10] + (v)[11])) + (((v)[12] + (v)[13]) + ((v)[14] + (v)[15]))))

// ---------------- pre: hist (blocks 0..255) + x->f16 cvt (rest) + sentinel zeroing ----------------
// NOTE: NO device-fence/ticket here — R16 showed per-block __threadfence across a
// large grid costs ~300ns each (520us total). Scan stays a separate tiny dispatch.
__global__ __launch_bounds__(256) void gnn_pre(const int* __restrict__ dst,
                                               int* __restrict__ bkt_cnt, int nbkt, int E,
                                               const int* __restrict__ batch,
                                               float* __restrict__ gcnt, int N,
                                               const float4* __restrict__ xin,
                                               ushort4* __restrict__ x16o, int n4,
                                               __half* __restrict__ x16,
                                               __half* __restrict__ hA,
                                               __half* __restrict__ hB) {
    int tid = threadIdx.x;
    if (blockIdx.x < HIST_BLOCKS) {
        __shared__ int h[512];
        __shared__ int gb[64];
        for (int i = tid; i < nbkt; i += 256) h[i] = 0;
        if (tid < 64) gb[tid] = 0;
        __syncthreads();
        const int stride = HIST_BLOCKS * 256;
        for (int e = blockIdx.x * 256 + tid; e < E; e += stride)
            atomicAdd(&h[dst[e] >> BSH], 1);
        for (int i = blockIdx.x * 256 + tid; i < N; i += stride)
            atomicAdd(&gb[batch[i]], 1);
        __syncthreads();
        for (int i = tid; i < nbkt; i += 256) {
            int v = h[i];
            if (v) atomicAdd(&bkt_cnt[i], v);
        }
        if (tid < 64) {
            int v = gb[tid];
            if (v) atomicAdd(&gcnt[tid], (float)v);
        }
        if (blockIdx.x == 0 && tid < 64) {  // zero sentinel row N of x16, hA, hB
            x16[(size_t)N * 64 + tid] = __ushort_as_half((unsigned short)0);
            hA[(size_t)N * 64 + tid] = __ushort_as_half((unsigned short)0);
            hB[(size_t)N * 64 + tid] = __ushort_as_half((unsigned short)0);
        }
    } else {
        int i = (blockIdx.x - HIST_BLOCKS) * 256 + tid;
        if (i < n4) {
            float4 f = xin[i];
            ushort4 o;
            o.x = __half_as_ushort(__float2half(f.x));
            o.y = __half_as_ushort(__float2half(f.y));
            o.z = __half_as_ushort(__float2half(f.z));
            o.w = __half_as_ushort(__float2half(f.w));
            x16o[i] = o;
        }
    }
}

// ---------------- bucket scan (1 wave) ----------------
__global__ void gnn_bkt_scan(const int* __restrict__ bkt_cnt, int* __restrict__ bkt_base,
                             int* __restrict__ bkt_cur, int* __restrict__ row_ptr,
                             int nbkt, int N) {
    int lane = threadIdx.x;
    int carry = 0;
    for (int base = 0; base < nbkt; base += 64) {
        int idx = base + lane;
        int v = (idx < nbkt) ? bkt_cnt[idx] : 0;
        int x = v;
#pragma unroll
        for (int off = 1; off < 64; off <<= 1) {
            int y = __shfl_up(x, off);
            if (lane >= off) x += y;
        }
        if (idx < nbkt) {
            bkt_base[idx] = carry + (x - v);
            bkt_cur[idx] = carry + (x - v);
        }
        carry += __shfl(x, 63);
    }
    if (lane == 0) {
        bkt_base[nbkt] = carry;
        row_ptr[N] = carry;
    }
}

// ---------------- block-aggregated two-phase scatter (packed uint32) ----------------
__global__ __launch_bounds__(256) void gnn_bkt_scatter(const int* __restrict__ src,
                                                       const int* __restrict__ dst,
                                                       int* __restrict__ bkt_cur,
                                                       unsigned int* __restrict__ pairs,
                                                       int E, int nbkt) {
    __shared__ int hist[512];
    __shared__ int cur[512];
    int tid = threadIdx.x;
    int chunk = (E + gridDim.x - 1) / gridDim.x;
    int e0 = blockIdx.x * chunk;
    int e1 = min(E, e0 + chunk);
    for (int i = tid; i < nbkt; i += 256) hist[i] = 0;
    __syncthreads();
    for (int e = e0 + tid; e < e1; e += 256) atomicAdd(&hist[dst[e] >> BSH], 1);
    __syncthreads();
    for (int b = tid; b < nbkt; b += 256) {
        int c = hist[b];
        cur[b] = c ? atomicAdd(&bkt_cur[b], c) : 0;
    }
    __syncthreads();
    for (int e = e0 + tid; e < e1; e += 256) {
        int d = dst[e];
        int b = d >> BSH;
        int p = atomicAdd(&cur[b], 1);
        pairs[p] = (unsigned int)src[e] | ((unsigned int)(d & (BNODES - 1)) << 24);
    }
}

// ---------------- per-bucket CSR finalize ----------------
__global__ __launch_bounds__(256) void gnn_bkt_csr(const unsigned int* __restrict__ pairs,
                                                   const int* __restrict__ bkt_base,
                                                   int* __restrict__ row_ptr,
                                                   float* __restrict__ inv_deg,
                                                   int* __restrict__ csr_src, int N) {
    __shared__ int hist[BNODES];
    __shared__ int excl[BNODES];
    __shared__ int cur[BNODES];
    int b = blockIdx.x;
    int base = bkt_base[b];
    int cnt = bkt_base[b + 1] - base;
    int nd0 = b << BSH;
    int tid = threadIdx.x;
    hist[tid] = 0;
    __syncthreads();
    for (int i = tid; i < cnt; i += 256) atomicAdd(&hist[pairs[base + i] >> 24], 1);
    __syncthreads();
    if (tid < 64) {
        int carry = 0;
#pragma unroll
        for (int c = 0; c < BNODES; c += 64) {
            int v = hist[c + tid];
            int x = v;
#pragma unroll
            for (int off = 1; off < 64; off <<= 1) {
                int y = __shfl_up(x, off);
                if (tid >= off) x += y;
            }
            excl[c + tid] = carry + (x - v);
            carry += __shfl(x, 63);
        }
    }
    __syncthreads();
    {
        int node = nd0 + tid;
        if (node < N) {
            row_ptr[node] = base + excl[tid];
            int d = hist[tid];
            inv_deg[node] = 1.0f / (float)(d > 1 ? d : 1);
        }
        cur[tid] = excl[tid];
    }
    __syncthreads();
    for (int i = tid; i < cnt; i += 256) {
        unsigned int u = pairs[base + i];
        int j = u >> 24;
        int pos = atomicAdd(&cur[j], 1);
        csr_src[base + pos] = (int)(u & 0xFFFFFFu);
    }
}

// ---------------- SAGE layer (R10/R14-verbatim body — do NOT reshape gather) ----------------
__global__ __launch_bounds__(512, 6) void gnn_sage(const __half* __restrict__ hin,
                                                   __half* __restrict__ hout,
                                                   const int* __restrict__ row_ptr,
                                                   const int* __restrict__ csr_src,
                                                   const float* __restrict__ inv_deg,
                                                   const float* __restrict__ Wl,
                                                   const float* __restrict__ bl,
                                                   const float* __restrict__ Wr, int n) {
    __shared__ _Float16 w_lds[64 * PADK];
    __shared__ _Float16 in_lds[WPB][16 * PADK];
    int tid = threadIdx.x, lane = tid & 63, wv = tid >> 6;
    for (int i = tid; i < 64 * 64; i += 512) {
        int k = i >> 6, nn = i & 63;
        w_lds[nn * PADK + k] = (_Float16)Wl[i];
        w_lds[nn * PADK + 64 + k] = (_Float16)Wr[i];
    }
    __syncthreads();
    int ngroups = (n + 15) >> 4;
    int g = blockIdx.x * WPB + wv;
    if (g >= ngroups) return;
    int m16 = lane & 15, quad = lane >> 4;
    float bias[4];
#pragma unroll
    for (int nt = 0; nt < 4; nt++) bias[nt] = bl[nt * 16 + m16];
    _Float16* my_in = in_lds[wv];
    const _Float16* hin16 = (const _Float16*)hin;
    int nd0 = g << 4;
    for (int j2 = 0; j2 < 16; j2 += 2) {
        int ndA = min(nd0 + j2, n - 1);
        int ndB = min(nd0 + j2 + 1, n - 1);
        int s0A = row_ptr[ndA], s1A = row_ptr[ndA + 1];
        int s0B = row_ptr[ndB], s1B = row_ptr[ndB + 1];
        float idgA = inv_deg[ndA], idgB = inv_deg[ndB];
        my_in[j2 * PADK + 64 + lane] = hin16[(size_t)ndA * 64 + lane];
        my_in[(j2 + 1) * PADK + 64 + lane] = hin16[(size_t)ndB * 64 + lane];
        float accA = 0.0f, accB = 0.0f;
        int cbA = min(64, s1A - s0A);
        int cbB = min(64, s1B - s0B);
        int eA = (lane < cbA) ? csr_src[s0A + lane] : n;
        int eB = (lane < cbB) ? csr_src[s0B + lane] : n;
#pragma unroll
        for (int ib = 0; ib < 4; ib++) {
            const int i0 = ib * 16;
            if (i0 < cbA) {
                float vA[16];
#pragma unroll
                for (int j = 0; j < 16; j++) {
                    int sj = __shfl(eA, i0 + j);
                    vA[j] = __half2float(hin[(size_t)sj * 64 + lane]);
                }
                accA += TS16(vA);
            }
            if (i0 < cbB) {
                float vB[16];
#pragma unroll
                for (int j = 0; j < 16; j++) {
                    int sj = __shfl(eB, i0 + j);
                    vB[j] = __half2float(hin[(size_t)sj * 64 + lane]);
                }
                accB += TS16(vB);
            }
        }
        for (int base = s0A + 64; base < s1A; base += 64) {
            int cb = min(64, s1A - base);
            int ei = (lane < cb) ? csr_src[base + lane] : n;
#pragma unroll
            for (int ib = 0; ib < 4; ib++) {
                const int i0 = ib * 16;
                if (i0 < cb) {
                    float v[16];
#pragma unroll
                    for (int j = 0; j < 16; j++) {
                        int s = __shfl(ei, i0 + j);
                        v[j] = __half2float(hin[(size_t)s * 64 + lane]);
                    }
                    accA += TS16(v);
                }
            }
        }
        for (int base = s0B + 64; base < s1B; base += 64) {
            int cb = min(64, s1B - base);
            int ei = (lane < cb) ? csr_src[base + lane] : n;
#pragma unroll
            for (int ib = 0; ib < 4; ib++) {
                const int i0 = ib * 16;
                if (i0 < cb) {
                    float v[16];
#pragma unroll
                    for (int j = 0; j < 16; j++) {
                        int s = __shfl(ei, i0 + j);
                        v[j] = __half2float(hin[(size_t)s * 64 + lane]);
                    }
                    accB += TS16(v);
                }
            }
        }
        my_in[j2 * PADK + lane] = (_Float16)(accA * idgA);
        my_in[(j2 + 1) * PADK + lane] = (_Float16)(accB * idgB);
    }
    half8 afrag[4];
    const _Float16* abase = my_in + m16 * PADK + quad * 8;
#pragma unroll
    for (int ks = 0; ks < 4; ks++) afrag[ks] = *(const half8*)(abase + ks * 32);
    floatx4 accv[4];
#pragma unroll
    for (int nt = 0; nt < 4; nt++) {
        accv[nt].x = 0.f; accv[nt].y = 0.f; accv[nt].z = 0.f; accv[nt].w = 0.f;
    }
#pragma unroll
    for (int nt = 0; nt < 4; nt++) {
        const _Float16* bbase = w_lds + (nt * 16 + m16) * PADK + quad * 8;
#pragma unroll
        for (int ks = 0; ks < 4; ks++) {
            half8 bfrag = *(const half8*)(bbase + ks * 32);
            accv[nt] = __builtin_amdgcn_mfma_f32_16x16x32_f16(afrag[ks], bfrag, accv[nt], 0, 0, 0);
        }
    }
#pragma unroll
    for (int nt = 0; nt < 4; nt++) {
#pragma unroll
        for (int r = 0; r < 4; r++) {
            int node = nd0 + quad * 4 + r;
            if (node < n) {
                float v = fmaxf(accv[nt][r] + bias[nt], 0.0f);
                hout[(size_t)node * 64 + nt * 16 + m16] = __float2half(v);
            }
        }
    }
}

// ---------------- SAGE layer 3 + fused global-mean-pool epilogue ----------------
__global__ __launch_bounds__(512, 6) void gnn_sage_pool(const __half* __restrict__ hin,
                                                        const int* __restrict__ row_ptr,
                                                        const int* __restrict__ csr_src,
                                                        const float* __restrict__ inv_deg,
                                                        const float* __restrict__ Wl,
                                                        const float* __restrict__ bl,
                                                        const float* __restrict__ Wr,
                                                        const int* __restrict__ batch,
                                                        float* __restrict__ gsum, int n) {
    __shared__ _Float16 w_lds[64 * PADK];
    __shared__ _Float16 in_lds[WPB][16 * PADK];
    int tid = threadIdx.x, lane = tid & 63, wv = tid >> 6;
    for (int i = tid; i < 64 * 64; i += 512) {
        int k = i >> 6, nn = i & 63;
        w_lds[nn * PADK + k] = (_Float16)Wl[i];
        w_lds[nn * PADK + 64 + k] = (_Float16)Wr[i];
    }
    __syncthreads();
    int ngroups = (n + 15) >> 4;
    int g = blockIdx.x * WPB + wv;
    if (g >= ngroups) return;
    int m16 = lane & 15, quad = lane >> 4;
    float bias[4];
#pragma unroll
    for (int nt = 0; nt < 4; nt++) bias[nt] = bl[nt * 16 + m16];
    _Float16* my_in = in_lds[wv];
    const _Float16* hin16 = (const _Float16*)hin;
    int nd0 = g << 4;
    for (int j2 = 0; j2 < 16; j2 += 2) {
        int ndA = min(nd0 + j2, n - 1);
        int ndB = min(nd0 + j2 + 1, n - 1);
        int s0A = row_ptr[ndA], s1A = row_ptr[ndA + 1];
        int s0B = row_ptr[ndB], s1B = row_ptr[ndB + 1];
        float idgA = inv_deg[ndA], idgB = inv_deg[ndB];
        my_in[j2 * PADK + 64 + lane] = hin16[(size_t)ndA * 64 + lane];
        my_in[(j2 + 1) * PADK + 64 + lane] = hin16[(size_t)ndB * 64 + lane];
        float accA = 0.0f, accB = 0.0f;
        int cbA = min(64, s1A - s0A);
        int cbB = min(64, s1B - s0B);
        int eA = (lane < cbA) ? csr_src[s0A + lane] : n;
        int eB = (lane < cbB) ? csr_src[s0B + lane] : n;
#pragma unroll
        for (int ib = 0; ib < 4; ib++) {
            const int i0 = ib * 16;
            if (i0 < cbA) {
                float vA[16];
#pragma unroll
                for (int j = 0; j < 16; j++) {
                    int sj = __shfl(eA, i0 + j);
                    vA[j] = __half2float(hin[(size_t)sj * 64 + lane]);
                }
                accA += TS16(vA);
            }
            if (i0 < cbB) {
                float vB[16];
#pragma unroll
                for (int j = 0; j < 16; j++) {
                    int sj = __shfl(eB, i0 + j);
                    vB[j] = __half2float(hin[(size_t)sj * 64 + lane]);
                }
                accB += TS16(vB);
            }
        }
        for (int base = s0A + 64; base < s1A; base += 64) {
            int cb = min(64, s1A - base);
            int ei = (lane < cb) ? csr_src[base + lane] : n;
#pragma unroll
            for (int ib = 0; ib < 4; ib++) {
                const int i0 = ib * 16;
                if (i0 < cb) {
                    float v[16];
#pragma unroll
                    for (int j = 0; j < 16; j++) {
                        int s = __shfl(ei, i0 + j);
                        v[j] = __half2float(hin[(size_t)s * 64 + lane]);
                    }
                    accA += TS16(v);
                }
            }
        }
        for (int base = s0B + 64; base < s1B; base += 64) {
            int cb = min(64, s1B - base);
            int ei = (lane < cb) ? csr_src[base + lane] : n;
#pragma unroll
            for (int ib = 0; ib < 4; ib++) {
                const int i0 = ib * 16;
                if (i0 < cb) {
                    float v[16];
#pragma unroll
                    for (int j = 0; j < 16; j++) {
                        int s = __shfl(ei, i0 + j);
                        v[j] = __half2float(hin[(size_t)s * 64 + lane]);
                    }
                    accB += TS16(v);
                }
            }
        }
        my_in[j2 * PADK + lane] = (_Float16)(accA * idgA);
        my_in[(j2 + 1) * PADK + lane] = (_Float16)(accB * idgB);
    }
    half8 afrag[4];
    const _Float16* abase = my_in + m16 * PADK + quad * 8;
#pragma unroll
    for (int ks = 0; ks < 4; ks++) afrag[ks] = *(const half8*)(abase + ks * 32);
    floatx4 accv[4];
#pragma unroll
    for (int nt = 0; nt < 4; nt++) {
        accv[nt].x = 0.f; accv[nt].y = 0.f; accv[nt].z = 0.f; accv[nt].w = 0.f;
    }
#pragma unroll
    for (int nt = 0; nt < 4; nt++) {
        const _Float16* bbase = w_lds + (nt * 16 + m16) * PADK + quad * 8;
#pragma unroll
        for (int ks = 0; ks < 4; ks++) {
            half8 bfrag = *(const half8*)(bbase + ks * 32);
            accv[nt] = __builtin_amdgcn_mfma_f32_16x16x32_f16(afrag[ks], bfrag, accv[nt], 0, 0, 0);
        }
    }
    // ---- fused pool epilogue ----
    int bFirst = batch[nd0];
    int bLast = batch[min(nd0 + 15, n - 1)];
    if (bFirst == bLast && nd0 + 15 < n) {
#pragma unroll
        for (int nt = 0; nt < 4; nt++) {
            float s = fmaxf(accv[nt][0] + bias[nt], 0.0f) + fmaxf(accv[nt][1] + bias[nt], 0.0f) +
                      fmaxf(accv[nt][2] + bias[nt], 0.0f) + fmaxf(accv[nt][3] + bias[nt], 0.0f);
            s += __shfl_xor(s, 16);
            s += __shfl_xor(s, 32);
            if (quad == 0) atomicAdd(&gsum[bFirst * 64 + nt * 16 + m16], s);
        }
    } else {
#pragma unroll
        for (int nt = 0; nt < 4; nt++) {
#pragma unroll
            for (int r = 0; r < 4; r++) {
                int node = nd0 + quad * 4 + r;
                if (node < n) {
                    int bg = batch[node];
                    float v = fmaxf(accv[nt][r] + bias[nt], 0.0f);
                    atomicAdd(&gsum[bg * 64 + nt * 16 + m16], v);
                }
            }
        }
    }
}

// ---------------- head ----------------
__global__ __launch_bounds__(256) void gnn_head(const float* __restrict__ gsum,
                                                const float* __restrict__ gcnt,
                                                const float* __restrict__ l0W,
                                                const float* __restrict__ l0b,
                                                const float* __restrict__ outW,
                                                const float* __restrict__ outb,
                                                float* __restrict__ out, int G, int OUT) {
    __shared__ float gm[64 * 64];
    __shared__ float t2[64 * 64];
    int tid = threadIdx.x;
    for (int i = tid; i < G * 64; i += 256) {
        int r = i >> 6;
        gm[i] = gsum[i] / fmaxf(gcnt[r], 1.0f);
    }
    __syncthreads();
    for (int i = tid; i < G * 64; i += 256) {
        int r = i >> 6, c = i & 63;
        float s = l0b[c];
#pragma unroll 8
        for (int k = 0; k < 64; k++) s += gm[(r << 6) + k] * l0W[(k << 6) + c];
        t2[i] = fmaxf(s, 0.0f);
    }
    __syncthreads();
    for (int i = tid; i < G * OUT; i += 256) {
        int r = i / OUT, c = i - r * OUT;
        float s = outb[c];
#pragma unroll 8
        for (int k = 0; k < 64; k++) s += t2[(r << 6) + k] * outW[k * OUT + c];
        out[i] = s;
    }
}

extern "C" void kernel_launch(void* const* d_in, const int* in_sizes, int n_in,
                              void* d_out, int out_size, void* d_ws, size_t ws_size,
                              hipStream_t stream) {
    const float* x = (const float*)d_in[0];
    const int* ei = (const int*)d_in[1];
    const int* batch = (const int*)d_in[2];
    const float* Wl[3] = {(const float*)d_in[3], (const float*)d_in[6], (const float*)d_in[9]};
    const float* bl[3] = {(const float*)d_in[4], (const float*)d_in[7], (const float*)d_in[10]};
    const float* Wr[3] = {(const float*)d_in[5], (const float*)d_in[8], (const float*)d_in[11]};
    const float* l0W = (const float*)d_in[12];
    const float* l0b = (const float*)d_in[13];
    const float* outW = (const float*)d_in[14];
    const float* outb = (const float*)d_in[15];

    int N = in_sizes[2];
    int E = in_sizes[1] / 2;
    int OUT = 10;
    int G = out_size / OUT;
    const int* src = ei;
    const int* dst = ei + E;
    int NBKT = (N + BNODES - 1) >> BSH;

    char* ws = (char*)d_ws;
    size_t off = 0;
    auto alloc = [&](size_t b) -> char* {
        char* p = ws + off;
        off = (off + b + 255) & ~(size_t)255;
        return p;
    };
    int* row_ptr = (int*)alloc((size_t)(N + 1) * 4);
    int* csr_src = (int*)alloc((size_t)E * 4);
    float* inv_deg = (float*)alloc((size_t)N * 4);
    // contiguous zero region: bkt_cnt | gcnt | gsum (one memset)
    size_t zoff = off;
    int* bkt_cnt = (int*)alloc((size_t)NBKT * 4);
    float* gcnt = (float*)alloc((size_t)G * 4);
    float* gsum = (float*)alloc((size_t)G * 64 * 4);
    size_t zlen = off - zoff;
    int* bkt_base = (int*)alloc((size_t)(NBKT + 1) * 4);
    int* bkt_cur = (int*)alloc((size_t)NBKT * 4);
    unsigned int* pairs = (unsigned int*)alloc((size_t)E * 4);
    __half* x16 = (__half*)alloc((size_t)(N + 1) * 64 * 2);  // +1 sentinel row
    __half* hA = (__half*)alloc((size_t)(N + 1) * 64 * 2);
    __half* hB = (__half*)alloc((size_t)(N + 1) * 64 * 2);

    hipMemsetAsync(ws + zoff, 0, zlen, stream);

    int n4 = N * 64 / 4;
    int pre_blocks = HIST_BLOCKS + (n4 + 255) / 256;
    gnn_pre<<<pre_blocks, 256, 0, stream>>>(dst, bkt_cnt, NBKT, E, batch, gcnt, N,
                                            (const float4*)x, (ushort4*)x16, n4,
                                            x16, hA, hB);
    gnn_bkt_scan<<<1, 64, 0, stream>>>(bkt_cnt, bkt_base, bkt_cur, row_ptr, NBKT, N);
    gnn_bkt_scatter<<<SC_BLOCKS, 256, 0, stream>>>(src, dst, bkt_cur, pairs, E, NBKT);
    gnn_bkt_csr<<<NBKT, 256, 0, stream>>>(pairs, bkt_base, row_ptr, inv_deg, csr_src, N);

    int ngroups = (N + 15) >> 4;
    int sage_blocks = (ngroups + WPB - 1) / WPB;
    gnn_sage<<<sage_blocks, 512, 0, stream>>>(x16, hA, row_ptr, csr_src, inv_deg,
                                              Wl[0], bl[0], Wr[0], N);
    gnn_sage<<<sage_blocks, 512, 0, stream>>>(hA, hB, row_ptr, csr_src, inv_deg,
                                              Wl[1], bl[1], Wr[1], N);
    gnn_sage_pool<<<sage_blocks, 512, 0, stream>>>(hB, row_ptr, csr_src, inv_deg,
                                                   Wl[2], bl[2], Wr[2], batch, gsum, N);

    gnn_head<<<1, 256, 0, stream>>>(gsum, gcnt, l0W, l0b, outW, outb, (float*)d_out, G, OUT);
}

// Round 18
// 345.296 us; speedup vs baseline: 2.3610x; 1.0158x over previous
//
#include <hip/hip_runtime.h>
#include <hip/hip_fp16.h>

#define WPB 8     // waves per sage block (512 threads)
#define PADK 136  // f16 elems per LDS row: 128 + 8 pad (16B-aligned rows)
#define BSH 8     // bucket shift: 256 nodes per bucket
#define BNODES 256
#define SC_BLOCKS 256   // MUST equal HIST_BLOCKS (chunk mapping shared)
#define HIST_BLOCKS 256
#define HSTRIDE 512     // padded bucket stride in hist_all / blk_base_all

typedef _Float16 half8 __attribute__((ext_vector_type(8)));
typedef float floatx4 __attribute__((ext_vector_type(4)));

#define TS16(v) (((((v)[0] + (v)[1]) + ((v)[2] + (v)[3])) + (((v)[4] + (v)[5]) + ((v)[6] + (v)[7]))) + \
                 ((((v)[8] + (v)[9]) + ((v)[10] + (v)[11])) + (((v)[12] + (v)[13]) + ((v)[14] + (v)[15]))))

// ---------------- pre: hist (blocks 0..255, persisted per-block) + x->f16 cvt (rest) ----------------
__global__ __launch_bounds__(256) void gnn_pre(const int* __restrict__ dst,
                                               int* __restrict__ bkt_cnt, int nbkt, int E,
                                               const int* __restrict__ batch,
                                               float* __restrict__ gcnt, int N,
                                               const float4* __restrict__ xin,
                                               ushort4* __restrict__ x16o, int n4,
                                               __half* __restrict__ x16,
                                               __half* __restrict__ hA,
                                               __half* __restrict__ hB,
                                               int* __restrict__ hist_all) {
    int tid = threadIdx.x;
    if (blockIdx.x < HIST_BLOCKS) {
        __shared__ int h[512];
        __shared__ int gb[64];
        for (int i = tid; i < nbkt; i += 256) h[i] = 0;
        if (tid < 64) gb[tid] = 0;
        __syncthreads();
        const int stride = HIST_BLOCKS * 256;
        for (int e = blockIdx.x * 256 + tid; e < E; e += stride)
            atomicAdd(&h[dst[e] >> BSH], 1);
        for (int i = blockIdx.x * 256 + tid; i < N; i += stride)
            atomicAdd(&gb[batch[i]], 1);
        __syncthreads();
        for (int i = tid; i < nbkt; i += 256) {
            int v = h[i];
            hist_all[blockIdx.x * HSTRIDE + i] = v;  // persist per-block chunk histogram
            if (v) atomicAdd(&bkt_cnt[i], v);
        }
        if (tid < 64) {
            int v = gb[tid];
            if (v) atomicAdd(&gcnt[tid], (float)v);
        }
        if (blockIdx.x == 0 && tid < 64) {  // zero sentinel row N of x16, hA, hB
            x16[(size_t)N * 64 + tid] = __ushort_as_half((unsigned short)0);
            hA[(size_t)N * 64 + tid] = __ushort_as_half((unsigned short)0);
            hB[(size_t)N * 64 + tid] = __ushort_as_half((unsigned short)0);
        }
    } else {
        int i = (blockIdx.x - HIST_BLOCKS) * 256 + tid;
        if (i < n4) {
            float4 f = xin[i];
            ushort4 o;
            o.x = __half_as_ushort(__float2half(f.x));
            o.y = __half_as_ushort(__float2half(f.y));
            o.z = __half_as_ushort(__float2half(f.z));
            o.w = __half_as_ushort(__float2half(f.w));
            x16o[i] = o;
        }
    }
}

// ---------------- bucket scan (1 wave) ----------------
__global__ void gnn_bkt_scan(const int* __restrict__ bkt_cnt, int* __restrict__ bkt_base,
                             int* __restrict__ row_ptr, int nbkt, int N) {
    int lane = threadIdx.x;
    int carry = 0;
    for (int base = 0; base < nbkt; base += 64) {
        int idx = base + lane;
        int v = (idx < nbkt) ? bkt_cnt[idx] : 0;
        int x = v;
#pragma unroll
        for (int off = 1; off < 64; off <<= 1) {
            int y = __shfl_up(x, off);
            if (lane >= off) x += y;
        }
        if (idx < nbkt) bkt_base[idx] = carry + (x - v);
        carry += __shfl(x, 63);
    }
    if (lane == 0) {
        bkt_base[nbkt] = carry;
        row_ptr[N] = carry;
    }
}

// ---------------- scan2: per-bucket exclusive scan over blocks -> exact scatter bases ----------------
// one block per bucket; NO atomics needed downstream.
__global__ __launch_bounds__(256) void gnn_scan2(const int* __restrict__ hist_all,
                                                 const int* __restrict__ bkt_base,
                                                 int* __restrict__ blk_base_all, int nbkt) {
    int b = blockIdx.x;
    int t = threadIdx.x, lane = t & 63, wv = t >> 6;
    __shared__ int wsum[4];
    int v = hist_all[t * HSTRIDE + b];
    int x = v;
#pragma unroll
    for (int off = 1; off < 64; off <<= 1) {
        int y = __shfl_up(x, off);
        if (lane >= off) x += y;
    }
    if (lane == 63) wsum[wv] = x;
    __syncthreads();
    int wexcl = 0;
    for (int w = 0; w < wv; w++) wexcl += wsum[w];
    blk_base_all[t * HSTRIDE + b] = bkt_base[b] + wexcl + (x - v);
}

// ---------------- deterministic scatter: LDS cursors from blk_base_all, zero global atomics ----------------
__global__ __launch_bounds__(256) void gnn_bkt_scatter(const int* __restrict__ src,
                                                       const int* __restrict__ dst,
                                                       const int* __restrict__ blk_base_all,
                                                       unsigned int* __restrict__ pairs,
                                                       int E, int nbkt) {
    __shared__ int cur[512];
    int tid = threadIdx.x;
    for (int i = tid; i < nbkt; i += 256) cur[i] = blk_base_all[blockIdx.x * HSTRIDE + i];
    __syncthreads();
    const int stride = SC_BLOCKS * 256;  // SAME chunk mapping as gnn_pre's histogram
    for (int e = blockIdx.x * 256 + tid; e < E; e += stride) {
        int d = dst[e];
        int b = d >> BSH;
        int p = atomicAdd(&cur[b], 1);  // LDS atomic only
        pairs[p] = (unsigned int)src[e] | ((unsigned int)(d & (BNODES - 1)) << 24);
    }
}

// ---------------- per-bucket CSR finalize ----------------
__global__ __launch_bounds__(256) void gnn_bkt_csr(const unsigned int* __restrict__ pairs,
                                                   const int* __restrict__ bkt_base,
                                                   int* __restrict__ row_ptr,
                                                   float* __restrict__ inv_deg,
                                                   int* __restrict__ csr_src, int N) {
    __shared__ int hist[BNODES];
    __shared__ int excl[BNODES];
    __shared__ int cur[BNODES];
    int b = blockIdx.x;
    int base = bkt_base[b];
    int cnt = bkt_base[b + 1] - base;
    int nd0 = b << BSH;
    int tid = threadIdx.x;
    hist[tid] = 0;
    __syncthreads();
    for (int i = tid; i < cnt; i += 256) atomicAdd(&hist[pairs[base + i] >> 24], 1);
    __syncthreads();
    if (tid < 64) {
        int carry = 0;
#pragma unroll
        for (int c = 0; c < BNODES; c += 64) {
            int v = hist[c + tid];
            int x = v;
#pragma unroll
            for (int off = 1; off < 64; off <<= 1) {
                int y = __shfl_up(x, off);
                if (tid >= off) x += y;
            }
            excl[c + tid] = carry + (x - v);
            carry += __shfl(x, 63);
        }
    }
    __syncthreads();
    {
        int node = nd0 + tid;
        if (node < N) {
            row_ptr[node] = base + excl[tid];
            int d = hist[tid];
            inv_deg[node] = 1.0f / (float)(d > 1 ? d : 1);
        }
        cur[tid] = excl[tid];
    }
    __syncthreads();
    for (int i = tid; i < cnt; i += 256) {
        unsigned int u = pairs[base + i];
        int j = u >> 24;
        int pos = atomicAdd(&cur[j], 1);
        csr_src[base + pos] = (int)(u & 0xFFFFFFu);
    }
}

// ---------------- SAGE layer (R10/R14-verbatim body — do NOT reshape gather) ----------------
__global__ __launch_bounds__(512, 6) void gnn_sage(const __half* __restrict__ hin,
                                                   __half* __restrict__ hout,
                                                   const int* __restrict__ row_ptr,
                                                   const int* __restrict__ csr_src,
                                                   const float* __restrict__ inv_deg,
                                                   const float* __restrict__ Wl,
                                                   const float* __restrict__ bl,
                                                   const float* __restrict__ Wr, int n) {
    __shared__ _Float16 w_lds[64 * PADK];
    __shared__ _Float16 in_lds[WPB][16 * PADK];
    int tid = threadIdx.x, lane = tid & 63, wv = tid >> 6;
    for (int i = tid; i < 64 * 64; i += 512) {
        int k = i >> 6, nn = i & 63;
        w_lds[nn * PADK + k] = (_Float16)Wl[i];
        w_lds[nn * PADK + 64 + k] = (_Float16)Wr[i];
    }
    __syncthreads();
    int ngroups = (n + 15) >> 4;
    int g = blockIdx.x * WPB + wv;
    if (g >= ngroups) return;
    int m16 = lane & 15, quad = lane >> 4;
    float bias[4];
#pragma unroll
    for (int nt = 0; nt < 4; nt++) bias[nt] = bl[nt * 16 + m16];
    _Float16* my_in = in_lds[wv];
    const _Float16* hin16 = (const _Float16*)hin;
    int nd0 = g << 4;
    for (int j2 = 0; j2 < 16; j2 += 2) {
        int ndA = min(nd0 + j2, n - 1);
        int ndB = min(nd0 + j2 + 1, n - 1);
        int s0A = row_ptr[ndA], s1A = row_ptr[ndA + 1];
        int s0B = row_ptr[ndB], s1B = row_ptr[ndB + 1];
        float idgA = inv_deg[ndA], idgB = inv_deg[ndB];
        my_in[j2 * PADK + 64 + lane] = hin16[(size_t)ndA * 64 + lane];
        my_in[(j2 + 1) * PADK + 64 + lane] = hin16[(size_t)ndB * 64 + lane];
        float accA = 0.0f, accB = 0.0f;
        int cbA = min(64, s1A - s0A);
        int cbB = min(64, s1B - s0B);
        int eA = (lane < cbA) ? csr_src[s0A + lane] : n;
        int eB = (lane < cbB) ? csr_src[s0B + lane] : n;
#pragma unroll
        for (int ib = 0; ib < 4; ib++) {
            const int i0 = ib * 16;
            if (i0 < cbA) {
                float vA[16];
#pragma unroll
                for (int j = 0; j < 16; j++) {
                    int sj = __shfl(eA, i0 + j);
                    vA[j] = __half2float(hin[(size_t)sj * 64 + lane]);
                }
                accA += TS16(vA);
            }
            if (i0 < cbB) {
                float vB[16];
#pragma unroll
                for (int j = 0; j < 16; j++) {
                    int sj = __shfl(eB, i0 + j);
                    vB[j] = __half2float(hin[(size_t)sj * 64 + lane]);
                }
                accB += TS16(vB);
            }
        }
        for (int base = s0A + 64; base < s1A; base += 64) {
            int cb = min(64, s1A - base);
            int ei = (lane < cb) ? csr_src[base + lane] : n;
#pragma unroll
            for (int ib = 0; ib < 4; ib++) {
                const int i0 = ib * 16;
                if (i0 < cb) {
                    float v[16];
#pragma unroll
                    for (int j = 0; j < 16; j++) {
                        int s = __shfl(ei, i0 + j);
                        v[j] = __half2float(hin[(size_t)s * 64 + lane]);
                    }
                    accA += TS16(v);
                }
            }
        }
        for (int base = s0B + 64; base < s1B; base += 64) {
            int cb = min(64, s1B - base);
            int ei = (lane < cb) ? csr_src[base + lane] : n;
#pragma unroll
            for (int ib = 0; ib < 4; ib++) {
                const int i0 = ib * 16;
                if (i0 < cb) {
                    float v[16];
#pragma unroll
                    for (int j = 0; j < 16; j++) {
                        int s = __shfl(ei, i0 + j);
                        v[j] = __half2float(hin[(size_t)s * 64 + lane]);
                    }
                    accB += TS16(v);
                }
            }
        }
        my_in[j2 * PADK + lane] = (_Float16)(accA * idgA);
        my_in[(j2 + 1) * PADK + lane] = (_Float16)(accB * idgB);
    }
    half8 afrag[4];
    const _Float16* abase = my_in + m16 * PADK + quad * 8;
#pragma unroll
    for (int ks = 0; ks < 4; ks++) afrag[ks] = *(const half8*)(abase + ks * 32);
    floatx4 accv[4];
#pragma unroll
    for (int nt = 0; nt < 4; nt++) {
        accv[nt].x = 0.f; accv[nt].y = 0.f; accv[nt].z = 0.f; accv[nt].w = 0.f;
    }
#pragma unroll
    for (int nt = 0; nt < 4; nt++) {
        const _Float16* bbase = w_lds + (nt * 16 + m16) * PADK + quad * 8;
#pragma unroll
        for (int ks = 0; ks < 4; ks++) {
            half8 bfrag = *(const half8*)(bbase + ks * 32);
            accv[nt] = __builtin_amdgcn_mfma_f32_16x16x32_f16(afrag[ks], bfrag, accv[nt], 0, 0, 0);
        }
    }
#pragma unroll
    for (int nt = 0; nt < 4; nt++) {
#pragma unroll
        for (int r = 0; r < 4; r++) {
            int node = nd0 + quad * 4 + r;
            if (node < n) {
                float v = fmaxf(accv[nt][r] + bias[nt], 0.0f);
                hout[(size_t)node * 64 + nt * 16 + m16] = __float2half(v);
            }
        }
    }
}

// ---------------- SAGE layer 3 + fused global-mean-pool epilogue ----------------
__global__ __launch_bounds__(512, 6) void gnn_sage_pool(const __half* __restrict__ hin,
                                                        const int* __restrict__ row_ptr,
                                                        const int* __restrict__ csr_src,
                                                        const float* __restrict__ inv_deg,
                                                        const float* __restrict__ Wl,
                                                        const float* __restrict__ bl,
                                                        const float* __restrict__ Wr,
                                                        const int* __restrict__ batch,
                                                        float* __restrict__ gsum, int n) {
    __shared__ _Float16 w_lds[64 * PADK];
    __shared__ _Float16 in_lds[WPB][16 * PADK];
    int tid = threadIdx.x, lane = tid & 63, wv = tid >> 6;
    for (int i = tid; i < 64 * 64; i += 512) {
        int k = i >> 6, nn = i & 63;
        w_lds[nn * PADK + k] = (_Float16)Wl[i];
        w_lds[nn * PADK + 64 + k] = (_Float16)Wr[i];
    }
    __syncthreads();
    int ngroups = (n + 15) >> 4;
    int g = blockIdx.x * WPB + wv;
    if (g >= ngroups) return;
    int m16 = lane & 15, quad = lane >> 4;
    float bias[4];
#pragma unroll
    for (int nt = 0; nt < 4; nt++) bias[nt] = bl[nt * 16 + m16];
    _Float16* my_in = in_lds[wv];
    const _Float16* hin16 = (const _Float16*)hin;
    int nd0 = g << 4;
    for (int j2 = 0; j2 < 16; j2 += 2) {
        int ndA = min(nd0 + j2, n - 1);
        int ndB = min(nd0 + j2 + 1, n - 1);
        int s0A = row_ptr[ndA], s1A = row_ptr[ndA + 1];
        int s0B = row_ptr[ndB], s1B = row_ptr[ndB + 1];
        float idgA = inv_deg[ndA], idgB = inv_deg[ndB];
        my_in[j2 * PADK + 64 + lane] = hin16[(size_t)ndA * 64 + lane];
        my_in[(j2 + 1) * PADK + 64 + lane] = hin16[(size_t)ndB * 64 + lane];
        float accA = 0.0f, accB = 0.0f;
        int cbA = min(64, s1A - s0A);
        int cbB = min(64, s1B - s0B);
        int eA = (lane < cbA) ? csr_src[s0A + lane] : n;
        int eB = (lane < cbB) ? csr_src[s0B + lane] : n;
#pragma unroll
        for (int ib = 0; ib < 4; ib++) {
            const int i0 = ib * 16;
            if (i0 < cbA) {
                float vA[16];
#pragma unroll
                for (int j = 0; j < 16; j++) {
                    int sj = __shfl(eA, i0 + j);
                    vA[j] = __half2float(hin[(size_t)sj * 64 + lane]);
                }
                accA += TS16(vA);
            }
            if (i0 < cbB) {
                float vB[16];
#pragma unroll
                for (int j = 0; j < 16; j++) {
                    int sj = __shfl(eB, i0 + j);
                    vB[j] = __half2float(hin[(size_t)sj * 64 + lane]);
                }
                accB += TS16(vB);
            }
        }
        for (int base = s0A + 64; base < s1A; base += 64) {
            int cb = min(64, s1A - base);
            int ei = (lane < cb) ? csr_src[base + lane] : n;
#pragma unroll
            for (int ib = 0; ib < 4; ib++) {
                const int i0 = ib * 16;
                if (i0 < cb) {
                    float v[16];
#pragma unroll
                    for (int j = 0; j < 16; j++) {
                        int s = __shfl(ei, i0 + j);
                        v[j] = __half2float(hin[(size_t)s * 64 + lane]);
                    }
                    accA += TS16(v);
                }
            }
        }
        for (int base = s0B + 64; base < s1B; base += 64) {
            int cb = min(64, s1B - base);
            int ei = (lane < cb) ? csr_src[base + lane] : n;
#pragma unroll
            for (int ib = 0; ib < 4; ib++) {
                const int i0 = ib * 16;
                if (i0 < cb) {
                    float v[16];
#pragma unroll
                    for (int j = 0; j < 16; j++) {
                        int s = __shfl(ei, i0 + j);
                        v[j] = __half2float(hin[(size_t)s * 64 + lane]);
                    }
                    accB += TS16(v);
                }
            }
        }
        my_in[j2 * PADK + lane] = (_Float16)(accA * idgA);
        my_in[(j2 + 1) * PADK + lane] = (_Float16)(accB * idgB);
    }
    half8 afrag[4];
    const _Float16* abase = my_in + m16 * PADK + quad * 8;
#pragma unroll
    for (int ks = 0; ks < 4; ks++) afrag[ks] = *(const half8*)(abase + ks * 32);
    floatx4 accv[4];
#pragma unroll
    for (int nt = 0; nt < 4; nt++) {
        accv[nt].x = 0.f; accv[nt].y = 0.f; accv[nt].z = 0.f; accv[nt].w = 0.f;
    }
#pragma unroll
    for (int nt = 0; nt < 4; nt++) {
        const _Float16* bbase = w_lds + (nt * 16 + m16) * PADK + quad * 8;
#pragma unroll
        for (int ks = 0; ks < 4; ks++) {
            half8 bfrag = *(const half8*)(bbase + ks * 32);
            accv[nt] = __builtin_amdgcn_mfma_f32_16x16x32_f16(afrag[ks], bfrag, accv[nt], 0, 0, 0);
        }
    }
    // ---- fused pool epilogue ----
    int bFirst = batch[nd0];
    int bLast = batch[min(nd0 + 15, n - 1)];
    if (bFirst == bLast && nd0 + 15 < n) {
#pragma unroll
        for (int nt = 0; nt < 4; nt++) {
            float s = fmaxf(accv[nt][0] + bias[nt], 0.0f) + fmaxf(accv[nt][1] + bias[nt], 0.0f) +
                      fmaxf(accv[nt][2] + bias[nt], 0.0f) + fmaxf(accv[nt][3] + bias[nt], 0.0f);
            s += __shfl_xor(s, 16);
            s += __shfl_xor(s, 32);
            if (quad == 0) atomicAdd(&gsum[bFirst * 64 + nt * 16 + m16], s);
        }
    } else {
#pragma unroll
        for (int nt = 0; nt < 4; nt++) {
#pragma unroll
            for (int r = 0; r < 4; r++) {
                int node = nd0 + quad * 4 + r;
                if (node < n) {
                    int bg = batch[node];
                    float v = fmaxf(accv[nt][r] + bias[nt], 0.0f);
                    atomicAdd(&gsum[bg * 64 + nt * 16 + m16], v);
                }
            }
        }
    }
}

// ---------------- head ----------------
__global__ __launch_bounds__(256) void gnn_head(const float* __restrict__ gsum,
                                                const float* __restrict__ gcnt,
                                                const float* __restrict__ l0W,
                                                const float* __restrict__ l0b,
                                                const float* __restrict__ outW,
                                                const float* __restrict__ outb,
                                                float* __restrict__ out, int G, int OUT) {
    __shared__ float gm[64 * 64];
    __shared__ float t2[64 * 64];
    int tid = threadIdx.x;
    for (int i = tid; i < G * 64; i += 256) {
        int r = i >> 6;
        gm[i] = gsum[i] / fmaxf(gcnt[r], 1.0f);
    }
    __syncthreads();
    for (int i = tid; i < G * 64; i += 256) {
        int r = i >> 6, c = i & 63;
        float s = l0b[c];
#pragma unroll 8
        for (int k = 0; k < 64; k++) s += gm[(r << 6) + k] * l0W[(k << 6) + c];
        t2[i] = fmaxf(s, 0.0f);
    }
    __syncthreads();
    for (int i = tid; i < G * OUT; i += 256) {
        int r = i / OUT, c = i - r * OUT;
        float s = outb[c];
#pragma unroll 8
        for (int k = 0; k < 64; k++) s += t2[(r << 6) + k] * outW[k * OUT + c];
        out[i] = s;
    }
}

extern "C" void kernel_launch(void* const* d_in, const int* in_sizes, int n_in,
                              void* d_out, int out_size, void* d_ws, size_t ws_size,
                              hipStream_t stream) {
    const float* x = (const float*)d_in[0];
    const int* ei = (const int*)d_in[1];
    const int* batch = (const int*)d_in[2];
    const float* Wl[3] = {(const float*)d_in[3], (const float*)d_in[6], (const float*)d_in[9]};
    const float* bl[3] = {(const float*)d_in[4], (const float*)d_in[7], (const float*)d_in[10]};
    const float* Wr[3] = {(const float*)d_in[5], (const float*)d_in[8], (const float*)d_in[11]};
    const float* l0W = (const float*)d_in[12];
    const float* l0b = (const float*)d_in[13];
    const float* outW = (const float*)d_in[14];
    const float* outb = (const float*)d_in[15];

    int N = in_sizes[2];
    int E = in_sizes[1] / 2;
    int OUT = 10;
    int G = out_size / OUT;
    const int* src = ei;
    const int* dst = ei + E;
    int NBKT = (N + BNODES - 1) >> BSH;

    char* ws = (char*)d_ws;
    size_t off = 0;
    auto alloc = [&](size_t b) -> char* {
        char* p = ws + off;
        off = (off + b + 255) & ~(size_t)255;
        return p;
    };
    int* row_ptr = (int*)alloc((size_t)(N + 1) * 4);
    int* csr_src = (int*)alloc((size_t)E * 4);
    float* inv_deg = (float*)alloc((size_t)N * 4);
    // contiguous zero region: bkt_cnt | gcnt | gsum (one memset)
    size_t zoff = off;
    int* bkt_cnt = (int*)alloc((size_t)NBKT * 4);
    float* gcnt = (float*)alloc((size_t)G * 4);
    float* gsum = (float*)alloc((size_t)G * 64 * 4);
    size_t zlen = off - zoff;
    int* bkt_base = (int*)alloc((size_t)(NBKT + 1) * 4);
    int* hist_all = (int*)alloc((size_t)HIST_BLOCKS * HSTRIDE * 4);
    int* blk_base_all = (int*)alloc((size_t)HIST_BLOCKS * HSTRIDE * 4);
    unsigned int* pairs = (unsigned int*)alloc((size_t)E * 4);
    __half* x16 = (__half*)alloc((size_t)(N + 1) * 64 * 2);  // +1 sentinel row
    __half* hA = (__half*)alloc((size_t)(N + 1) * 64 * 2);
    __half* hB = (__half*)alloc((size_t)(N + 1) * 64 * 2);

    hipMemsetAsync(ws + zoff, 0, zlen, stream);

    int n4 = N * 64 / 4;
    int pre_blocks = HIST_BLOCKS + (n4 + 255) / 256;
    gnn_pre<<<pre_blocks, 256, 0, stream>>>(dst, bkt_cnt, NBKT, E, batch, gcnt, N,
                                            (const float4*)x, (ushort4*)x16, n4,
                                            x16, hA, hB, hist_all);
    gnn_bkt_scan<<<1, 64, 0, stream>>>(bkt_cnt, bkt_base, row_ptr, NBKT, N);
    gnn_scan2<<<NBKT, 256, 0, stream>>>(hist_all, bkt_base, blk_base_all, NBKT);
    gnn_bkt_scatter<<<SC_BLOCKS, 256, 0, stream>>>(src, dst, blk_base_all, pairs, E, NBKT);
    gnn_bkt_csr<<<NBKT, 256, 0, stream>>>(pairs, bkt_base, row_ptr, inv_deg, csr_src, N);

    int ngroups = (N + 15) >> 4;
    int sage_blocks = (ngroups + WPB - 1) / WPB;
    gnn_sage<<<sage_blocks, 512, 0, stream>>>(x16, hA, row_ptr, csr_src, inv_deg,
                                              Wl[0], bl[0], Wr[0], N);
    gnn_sage<<<sage_blocks, 512, 0, stream>>>(hA, hB, row_ptr, csr_src, inv_deg,
                                              Wl[1], bl[1], Wr[1], N);
    gnn_sage_pool<<<sage_blocks, 512, 0, stream>>>(hB, row_ptr, csr_src, inv_deg,
                                                   Wl[2], bl[2], Wr[2], batch, gsum, N);

    gnn_head<<<1, 256, 0, stream>>>(gsum, gcnt, l0W, l0b, outW, outb, (float*)d_out, G, OUT);
}